// Round 9
// baseline (471.841 us; speedup 1.0000x reference)
//
#include <hip/hip_runtime.h>

#define NN 50000
#define EE 800000
#define FHID 128
#define NHEAD 4
#define NGRAPH 512
#define NCLS 10
#define BK 256            // buckets (dst>>8)
#define BCH 4096          // edges per block in bin kernel
#define NBLK_E 196        // ceil(EE/BCH)
#define NBUCK 196         // ceil(NN/256)
#define CAPB 6144         // slack capacity per bucket (mean 4096, 32-sigma headroom)

typedef unsigned short u16;
typedef unsigned int u32;
typedef unsigned long long u64;
typedef __attribute__((ext_vector_type(8))) short bf16x8;
typedef __attribute__((ext_vector_type(4))) float f32x4;

__device__ __forceinline__ float bf2f(u16 u){
    union { u32 i; float f; } v; v.i = ((u32)u) << 16; return v.f;
}
__device__ __forceinline__ float bflo(u32 u){
    union { u32 i; float f; } v; v.i = u << 16; return v.f;
}
__device__ __forceinline__ float bfhi(u32 u){
    union { u32 i; float f; } v; v.i = u & 0xffff0000u; return v.f;
}
__device__ __forceinline__ u16 f2bf(float f){
    union { float f; u32 i; } v; v.f = f;
    u32 r = v.i + 0x7fffu + ((v.i >> 16) & 1u);
    return (u16)(r >> 16);
}
__device__ __forceinline__ u32 pack2(float a, float b){
    return ((u32)f2bf(b) << 16) | f2bf(a);
}
__device__ __forceinline__ float loadF(const void* p, int i, int isf32){
    return isf32 ? ((const float*)p)[i] : bf2f(((const u16*)p)[i]);
}
__device__ __forceinline__ void unpk8(uint4 v, float* f){
    f[0]=bflo(v.x); f[1]=bfhi(v.x);
    f[2]=bflo(v.y); f[3]=bfhi(v.y);
    f[4]=bflo(v.z); f[5]=bfhi(v.z);
    f[6]=bflo(v.w); f[7]=bfhi(v.w);
}

// block-local dtype detect: count bf16-plausible halfwords in x[0..1023] (lds reduce)
__device__ int detect_local(const u16* x, int tid, int nthreads, int* lds){
    int ok = 0;
    for (int i = tid; i < 1024; i += nthreads){
        u16 u = x[i];
        int e = (u >> 7) & 0xFF;
        if ((u & 0x7fff) == 0 || (e >= 0x70 && e <= 0x85)) ok++;
    }
    lds[tid] = ok;
    __syncthreads();
    for (int o2 = nthreads >> 1; o2 > 0; o2 >>= 1){
        if (tid < o2) lds[tid] += lds[tid + o2];
        __syncthreads();
    }
    int r = (lds[0] < 900) ? 1 : 0;   // 1 = f32 inputs
    __syncthreads();
    return r;
}

// ---------------- fused prep: weights (blocks 0..511) + head/att (512..527) ---------
// block 0 also initializes gcur[t] = t*CAPB (slack-bucket bases)
__global__ __launch_bounds__(256) void prep_all(
        const u16* __restrict__ xz,
        const void* w_feat, const void* b_feat, const void* bn_feat_g, const void* bn_feat_b,
        const void* w_gat, const void* bn_conv_g, const void* bn_conv_b, const void* b_gat,
        const void* wfc, const void* bfc, const void* bnfg, const void* bnfb,
        const void* bnhg, const void* bnhb, const void* wcls, const void* bcls,
        const void* attl, const void* attr,
        u16* __restrict__ Wt, float* __restrict__ cvec, float* __restrict__ biasv,
        float* __restrict__ hp, int* __restrict__ dflag, int* __restrict__ gcur)
{
    __shared__ int ldsi[256];
    __shared__ float red[128];
    int bid = blockIdx.x, t = threadIdx.x;
    int isf32 = detect_local(xz, t, 256, ldsi);
    if (bid == 0){
        if (t == 0) dflag[0] = isf32;
        gcur[t] = t * CAPB;
    }

    if (bid < 512){
        if (t >= 128) return;
        int L = bid >> 7;
        int n = bid & 127;
        int k = t;
        const float rs = rsqrtf(1.0f + 1e-5f);
        float wv, bg, bb;
        if (L == 0){
            wv = loadF(w_feat, k*FHID + n, isf32);
            bg = loadF(bn_feat_g, k, isf32);
            bb = loadF(bn_feat_b, k, isf32);
        } else {
            wv = loadF(w_gat, (L-1)*FHID*FHID + k*FHID + n, isf32);
            bg = loadF(bn_conv_g, (L-1)*FHID + k, isf32);
            bb = loadF(bn_conv_b, (L-1)*FHID + k, isf32);
        }
        Wt[L*FHID*FHID + n*FHID + k] = f2bf(bg * rs * wv);
        red[k] = bb * wv;
        __syncthreads();
        for (int o2 = 64; o2 > 0; o2 >>= 1){
            if (k < o2) red[k] += red[k + o2];
            __syncthreads();
        }
        if (k == 0){
            float c = red[0];
            if (L == 0) c += loadF(b_feat, n, isf32);
            cvec[L*FHID + n] = c;
            if (L > 0) biasv[L*FHID + n] = loadF(b_gat, (L-1)*FHID + n, isf32);
        }
    } else {
        int gt = (bid - 512)*256 + t;
        for (int i = gt; i < FHID*FHID; i += 16*256) hp[i] = loadF(wfc, i, isf32);
        if (gt < FHID*NCLS) hp[16384 + gt] = loadF(wcls, gt, isf32);
        if (gt >= 2048 && gt < 2048 + 3*FHID){
            int i = gt - 2048;
            hp[18320 + i] = loadF(attl, i, isf32);
            hp[18704 + i] = loadF(attr, i, isf32);
        }
        if (gt >= 2560 && gt < 2560 + FHID){
            int tt = gt - 2560;
            hp[17664 + tt] = loadF(bnfg, tt, isf32);
            hp[17792 + tt] = loadF(bnfb, tt, isf32);
            hp[17920 + tt] = loadF(bfc,  tt, isf32);
            hp[18048 + tt] = loadF(bnhg, tt, isf32);
            hp[18176 + tt] = loadF(bnhb, tt, isf32);
        }
        if (gt >= 3072 && gt < 3072 + NCLS) hp[18304 + (gt - 3072)] = loadF(bcls, gt - 3072, isf32);
    }
}

// ---------------- MFMA GEMM: swapped operands + fused node_alpha epilogue -----------
__global__ __launch_bounds__(256) void gemm128(const void* __restrict__ A,
                                               const u16* __restrict__ Wt,
                                               const float* __restrict__ cvec,
                                               u16* __restrict__ out, int relu,
                                               int araw, const int* __restrict__ flag,
                                               const float* __restrict__ attl,
                                               const float* __restrict__ attr,
                                               float* __restrict__ al,
                                               float* __restrict__ ar)
{
    int wave = threadIdx.x >> 6;
    int lane = threadIdx.x & 63;
    int m = lane & 15, quad = lane >> 4;
    int rowbase = blockIdx.x * 128 + wave * 32;
    bool f32in = araw && flag[0];
    const u16*  Au = (const u16*)A;
    const float* Af = (const float*)A;
    int r0 = rowbase + m, r1 = rowbase + 16 + m;
    bool v0 = r0 < NN, v1 = r1 < NN;
    f32x4 acc[2][8];
#pragma unroll
    for (int i = 0; i < 2; i++)
#pragma unroll
        for (int j = 0; j < 8; j++) acc[i][j] = (f32x4){0.f,0.f,0.f,0.f};
#pragma unroll
    for (int t = 0; t < 4; t++){
        bf16x8 a0 = {0,0,0,0,0,0,0,0}, a1 = {0,0,0,0,0,0,0,0};
        int kof = t*32 + quad*8;
        if (f32in){
            if (v0){
                const float* p = Af + (size_t)r0*FHID + kof;
                float4 u0 = *(const float4*)p, u1 = *(const float4*)(p+4);
                a0[0]=(short)f2bf(u0.x); a0[1]=(short)f2bf(u0.y);
                a0[2]=(short)f2bf(u0.z); a0[3]=(short)f2bf(u0.w);
                a0[4]=(short)f2bf(u1.x); a0[5]=(short)f2bf(u1.y);
                a0[6]=(short)f2bf(u1.z); a0[7]=(short)f2bf(u1.w);
            }
            if (v1){
                const float* p = Af + (size_t)r1*FHID + kof;
                float4 u0 = *(const float4*)p, u1 = *(const float4*)(p+4);
                a1[0]=(short)f2bf(u0.x); a1[1]=(short)f2bf(u0.y);
                a1[2]=(short)f2bf(u0.z); a1[3]=(short)f2bf(u0.w);
                a1[4]=(short)f2bf(u1.x); a1[5]=(short)f2bf(u1.y);
                a1[6]=(short)f2bf(u1.z); a1[7]=(short)f2bf(u1.w);
            }
        } else {
            if (v0) a0 = *(const bf16x8*)(Au + (size_t)r0*FHID + kof);
            if (v1) a1 = *(const bf16x8*)(Au + (size_t)r1*FHID + kof);
        }
#pragma unroll
        for (int ct = 0; ct < 8; ct++){
            bf16x8 wfrag = *(const bf16x8*)(Wt + (ct*16 + m)*FHID + kof);
            acc[0][ct] = __builtin_amdgcn_mfma_f32_16x16x32_bf16(wfrag, a0, acc[0][ct], 0, 0, 0);
            acc[1][ct] = __builtin_amdgcn_mfma_f32_16x16x32_bf16(wfrag, a1, acc[1][ct], 0, 0, 0);
        }
    }
    bool doa = (attl != nullptr);
#pragma unroll
    for (int tt = 0; tt < 2; tt++){
        int row = rowbase + tt*16 + m;
        bool rv = row < NN;
        float sl[4] = {0.f,0.f,0.f,0.f};
        float sr[4] = {0.f,0.f,0.f,0.f};
#pragma unroll
        for (int ct = 0; ct < 8; ct++){
            int cb = ct*16 + quad*4;
            float4 cv = *(const float4*)(cvec + cb);
            float w0 = acc[tt][ct][0] + cv.x;
            float w1 = acc[tt][ct][1] + cv.y;
            float w2 = acc[tt][ct][2] + cv.z;
            float w3 = acc[tt][ct][3] + cv.w;
            if (relu){
                w0 = fmaxf(w0, 0.f); w1 = fmaxf(w1, 0.f);
                w2 = fmaxf(w2, 0.f); w3 = fmaxf(w3, 0.f);
            }
            if (doa){
                int h = ct >> 1;
                float4 tl = *(const float4*)(attl + cb);
                float4 tr = *(const float4*)(attr + cb);
                sl[h] += w0*tl.x + w1*tl.y + w2*tl.z + w3*tl.w;
                sr[h] += w0*tr.x + w1*tr.y + w2*tr.z + w3*tr.w;
            }
            if (rv){
                uint2 st; st.x = pack2(w0, w1); st.y = pack2(w2, w3);
                *(uint2*)(out + (size_t)row*FHID + cb) = st;
            }
        }
        if (doa){
#pragma unroll
            for (int h = 0; h < 4; h++){
                sl[h] += __shfl_xor(sl[h], 16, 64);
                sl[h] += __shfl_xor(sl[h], 32, 64);
                sr[h] += __shfl_xor(sr[h], 16, 64);
                sr[h] += __shfl_xor(sr[h], 32, 64);
            }
            if (rv){
                al[row*NHEAD + quad] = sl[quad];
                ar[row*NHEAD + quad] = sr[quad];
            }
        }
    }
}

// ---------------- bin edges into slack buckets (no global histogram needed) ---------
__global__ __launch_bounds__(256) void bin_edges(const int* __restrict__ srcp,
        const int* __restrict__ dstp, int* __restrict__ gcur, u64* __restrict__ binned)
{
    __shared__ int h[BK], lb[BK], gb[BK], cur[BK];
    __shared__ u64 stage[BCH];
    int t = threadIdx.x;
    h[t] = 0;
    __syncthreads();
    int base = blockIdx.x * BCH;
    int sv[16], dv[16];
#pragma unroll
    for (int k = 0; k < 16; k++){
        int e = base + k*256 + t;
        int d = -1, s = 0;
        if (e < EE){
            d = dstp[e]; s = srcp[e];
            if ((u32)d >= NN) d = -1;
        }
        sv[k] = s; dv[k] = d;
        if (d >= 0) atomicAdd(&h[d >> 8], 1);
    }
    __syncthreads();
    lb[t] = h[t];
    __syncthreads();
    for (int off = 1; off < BK; off <<= 1){
        int x = (t >= off) ? lb[t - off] : 0;
        __syncthreads();
        lb[t] += x;
        __syncthreads();
    }
    int excl = lb[t] - h[t];
    int tot  = lb[BK-1];
    __syncthreads();
    lb[t] = excl;
    gb[t] = h[t] ? atomicAdd(&gcur[t], h[t]) : 0;
    cur[t] = 0;
    __syncthreads();
#pragma unroll
    for (int k = 0; k < 16; k++){
        int d = dv[k];
        if (d >= 0){
            int b = d >> 8;
            int p = lb[b] + atomicAdd(&cur[b], 1);
            stage[p] = ((u64)(u32)d << 32) | (u32)sv[k];
        }
    }
    __syncthreads();
    for (int i = t; i < tot; i += 256){
        u64 pr = stage[i];
        int b = (int)(pr >> 40);
        binned[gb[b] + (i - lb[b])] = pr;
    }
}

// ---------------- per-bucket CSR: rowdeg int2 {start,end} into slack colbuf ---------
__global__ __launch_bounds__(256) void build_csr(const u64* __restrict__ binned,
        const int* __restrict__ gcur, int2* __restrict__ rowdeg, int* __restrict__ colbuf)
{
    __shared__ int deg[BK], ls[BK], cur[BK];
    __shared__ int colstage[CAPB];
    int b = blockIdx.x, t = threadIdx.x;
    int gb = b * CAPB;
    int cnt = gcur[b] - gb;
    if (cnt < 0) cnt = 0;
    if (cnt > CAPB) cnt = CAPB;
    deg[t] = 0;
    __syncthreads();
    for (int i = t; i < cnt; i += 256){
        int d = (int)(binned[gb + i] >> 32);
        atomicAdd(&deg[d & 255], 1);
    }
    __syncthreads();
    ls[t] = deg[t];
    __syncthreads();
    for (int off = 1; off < BK; off <<= 1){
        int x = (t >= off) ? ls[t - off] : 0;
        __syncthreads();
        ls[t] += x;
        __syncthreads();
    }
    int excl = ls[t] - deg[t];
    int node = b*256 + t;
    if (node < NN) rowdeg[node] = (int2){gb + excl, gb + excl + deg[t]};
    cur[t] = excl;
    __syncthreads();
    for (int i = t; i < cnt; i += 256){
        u64 pr = binned[gb + i];
        int d = (int)(pr >> 32) & 255;
        int s = (int)(u32)pr;
        int p = atomicAdd(&cur[d], 1);
        colstage[p] = s;
    }
    __syncthreads();
    for (int i = t; i < cnt; i += 256) colbuf[gb + i] = colstage[i];
}

// ---------------- SuperGAT conv: 4 nodes/wave, 16 lanes/node, 8-wide edge unroll ----
__global__ __launch_bounds__(256) void supergat_conv(const u16* __restrict__ hh,
        const float* __restrict__ al, const float* __restrict__ ar,
        const int2* __restrict__ rowdeg, const int* __restrict__ colbuf,
        const float* __restrict__ bias, u16* __restrict__ hout)
{
    int wid  = (blockIdx.x*256 + threadIdx.x) >> 6;
    int lane = threadIdx.x & 63;
    int group = lane >> 4;
    int gl    = lane & 15;
    int head  = gl >> 2;
    int q     = gl & 3;
    int node  = wid*4 + group;
    bool valid = node < NN;
    int snode = valid ? node : 0;
    int chbase = head*32 + q*8;

    uint4 hdv = *(const uint4*)(hh + (size_t)snode*FHID + chbase);
    float hd[8]; unpk8(hdv, hd);
    float arn = ar[snode*NHEAD + head];
    float aln = al[snode*NHEAD + head];

    float d = hd[0]*hd[0]+hd[1]*hd[1]+hd[2]*hd[2]+hd[3]*hd[3]
            + hd[4]*hd[4]+hd[5]*hd[5]+hd[6]*hd[6]+hd[7]*hd[7];
    d += __shfl_xor(d, 1, 64);
    d += __shfl_xor(d, 2, 64);
    float a = (aln + arn) * (1.0f / (1.0f + __expf(-d)));
    a = (a > 0.0f) ? a : 0.2f*a;
    float p = __expf(fminf(a, 60.f));
    float s = p;
    float o[8];
#pragma unroll
    for (int i = 0; i < 8; i++) o[i] = p*hd[i];

    int2 rd = valid ? rowdeg[node] : (int2){0,0};
    int e0 = rd.x, e1 = rd.y;
    if (e0 < 0) e0 = 0;
    if (e1 > BK*CAPB) e1 = BK*CAPB;

    int e = e0;
    while (e + 7 < e1){
        int sidx[8];
#pragma unroll
        for (int j = 0; j < 8; j++){
            int si = colbuf[e + j];
            if ((u32)si >= NN) si = 0;
            sidx[j] = si;
        }
        uint4 xv[8]; float af[8];
#pragma unroll
        for (int j = 0; j < 8; j++){
            xv[j] = *(const uint4*)(hh + (size_t)sidx[j]*FHID + chbase);
            af[j] = al[sidx[j]*NHEAD + head];
        }
#pragma unroll
        for (int j = 0; j < 8; j++){
            float hs[8]; unpk8(xv[j], hs);
            float lg = hd[0]*hs[0]+hd[1]*hs[1]+hd[2]*hs[2]+hd[3]*hs[3]
                     + hd[4]*hs[4]+hd[5]*hs[5]+hd[6]*hs[6]+hd[7]*hs[7];
            lg += __shfl_xor(lg, 1, 64);
            lg += __shfl_xor(lg, 2, 64);
            float a2 = (af[j] + arn) * (1.0f / (1.0f + __expf(-lg)));
            a2 = (a2 > 0.0f) ? a2 : 0.2f*a2;
            float pe = __expf(fminf(a2, 60.f));
            s += pe;
#pragma unroll
            for (int i = 0; i < 8; i++) o[i] += pe*hs[i];
        }
        e += 8;
    }
    while (e < e1){
        int si = colbuf[e];
        if ((u32)si >= NN) si = 0;
        uint4 x1 = *(const uint4*)(hh + (size_t)si*FHID + chbase);
        float af1 = al[si*NHEAD + head];
        float hs[8]; unpk8(x1, hs);
        float lg = hd[0]*hs[0]+hd[1]*hs[1]+hd[2]*hs[2]+hd[3]*hs[3]
                 + hd[4]*hs[4]+hd[5]*hs[5]+hd[6]*hs[6]+hd[7]*hs[7];
        lg += __shfl_xor(lg, 1, 64);
        lg += __shfl_xor(lg, 2, 64);
        float a2 = (af1 + arn) * (1.0f / (1.0f + __expf(-lg)));
        a2 = (a2 > 0.0f) ? a2 : 0.2f*a2;
        float pe = __expf(fminf(a2, 60.f));
        s += pe;
#pragma unroll
        for (int i = 0; i < 8; i++) o[i] += pe*hs[i];
        e++;
    }

    if (valid){
        float inv = 1.0f / (s + 1e-16f);
        uint4 w;
        w.x = pack2(fmaxf(o[0]*inv + bias[chbase+0], 0.f),
                    fmaxf(o[1]*inv + bias[chbase+1], 0.f));
        w.y = pack2(fmaxf(o[2]*inv + bias[chbase+2], 0.f),
                    fmaxf(o[3]*inv + bias[chbase+3], 0.f));
        w.z = pack2(fmaxf(o[4]*inv + bias[chbase+4], 0.f),
                    fmaxf(o[5]*inv + bias[chbase+5], 0.f));
        w.w = pack2(fmaxf(o[6]*inv + bias[chbase+6], 0.f),
                    fmaxf(o[7]*inv + bias[chbase+7], 0.f));
        *(uint4*)(hout + (size_t)node*FHID + chbase) = w;
    }
}

// ---------------- fused pool + head: one block per graph ----------------------------
__global__ void pool_head(const u16* __restrict__ h, const int* __restrict__ batch,
                          const float* __restrict__ hp, const int* __restrict__ flag,
                          void* __restrict__ out)
{
    __shared__ int bounds[2];
    __shared__ float gb[FHID];
    __shared__ float g2[FHID];
    __shared__ float lg[16];
    int gi = blockIdx.x, t = threadIdx.x;
    int isf32 = flag[0];
    if (t < 2){
        int target = gi + t;
        int lo = 0, hi = NN;
        while (lo < hi){
            int mid = (lo + hi) >> 1;
            if (batch[mid] < target) lo = mid + 1; else hi = mid;
        }
        bounds[t] = lo;
    }
    __syncthreads();
    float acc0 = 0.f;
    for (int node = bounds[0]; node < bounds[1]; node++)
        acc0 += bf2f(h[(size_t)node*FHID + t]);
    const float rs = rsqrtf(1.0f + 1e-5f);
    gb[t] = acc0 * (hp[17664 + t] * rs) + hp[17792 + t];
    __syncthreads();
    float acc = hp[17920 + t];
    for (int k = 0; k < FHID; k++) acc += gb[k] * hp[k*FHID + t];
    acc = fmaxf(acc, 0.f);
    g2[t] = acc * (hp[18048 + t] * rs) + hp[18176 + t];
    __syncthreads();
    if (t < NCLS){
        float l = hp[18304 + t];
        for (int k = 0; k < FHID; k++) l += g2[k] * hp[16384 + k*NCLS + t];
        lg[t] = l;
    }
    __syncthreads();
    if (t == 0){
        float mx = lg[0];
        for (int j = 1; j < NCLS; j++) mx = fmaxf(mx, lg[j]);
        float se = 0.f;
        for (int j = 0; j < NCLS; j++) se += __expf(lg[j] - mx);
        float lse = logf(se) + mx;
        if (isf32){
            float* o = (float*)out;
            for (int j = 0; j < NCLS; j++) o[gi*NCLS + j] = lg[j] - lse;
            if (gi == 0) o[NGRAPH*NCLS] = 0.f;
        } else {
            u16* o = (u16*)out;
            for (int j = 0; j < NCLS; j++) o[gi*NCLS + j] = f2bf(lg[j] - lse);
            if (gi == 0) o[NGRAPH*NCLS] = 0;
        }
    }
}

extern "C" void kernel_launch(void* const* d_in, const int* in_sizes, int n_in,
                              void* d_out, int out_size, void* d_ws, size_t ws_size,
                              hipStream_t stream)
{
    (void)in_sizes; (void)n_in; (void)out_size; (void)ws_size;
    const void* x         = d_in[0];
    const int* edge       = (const int*)d_in[1];
    const int* batch      = (const int*)d_in[2];

    char* ws = (char*)d_ws;
    size_t off = 0;
    auto alloc = [&](size_t bytes) -> char* {
        char* p = ws + off; off += (bytes + 255) & ~(size_t)255; return p;
    };
    int*   dflag   = (int*)  alloc(256);
    u16*   WtAll   = (u16*)  alloc((size_t)4*FHID*FHID*2);
    float* cvecAll = (float*)alloc((size_t)4*FHID*4);
    float* biasv   = (float*)alloc((size_t)4*FHID*4);
    float* headp   = (float*)alloc((size_t)19088*4);
    float* al      = (float*)alloc((size_t)NN*NHEAD*4);
    float* ar      = (float*)alloc((size_t)NN*NHEAD*4);
    int*   gcur    = (int*)  alloc((size_t)BK*4);
    int2*  rowdeg  = (int2*) alloc((size_t)NN*8);
    int*   colbuf  = (int*)  alloc((size_t)BK*CAPB*4);     // 6.3 MB slack layout
    u16*   hA      = (u16*)  alloc((size_t)NN*FHID*2);
    u16*   hB      = (u16*)  alloc((size_t)NN*FHID*2);
    // binned (256*6144*8 = 12.58 MB) aliases hB (12.8 MB): hB first written by the
    // layer-1 gemm, strictly after build_csr (stream-ordered).
    u64*   binned  = (u64*)hB;

    const int* srcp = edge;
    const int* dstp = edge + EE;

    prep_all<<<528, 256, 0, stream>>>((const u16*)x,
        d_in[5], d_in[6], d_in[3], d_in[4], d_in[9], d_in[7], d_in[8], d_in[12],
        d_in[15], d_in[16], d_in[13], d_in[14], d_in[17], d_in[18], d_in[19], d_in[20],
        d_in[10], d_in[11],
        WtAll, cvecAll, biasv, headp, dflag, gcur);

    bin_edges<<<NBLK_E, 256, 0, stream>>>(srcp, dstp, gcur, binned);
    build_csr<<<NBUCK, 256, 0, stream>>>(binned, gcur, rowdeg, colbuf);

    // feature layer: reads raw x (f32 or bf16 per flag), converts in-register
    gemm128<<<(NN + 127)/128, 256, 0, stream>>>(x, WtAll, cvecAll, hA, 1, 1, dflag,
                                                nullptr, nullptr, nullptr, nullptr);

    for (int i = 0; i < 3; i++){
        gemm128<<<(NN + 127)/128, 256, 0, stream>>>(hA, WtAll + (i+1)*FHID*FHID,
                                                    cvecAll + (i+1)*FHID, hB, 0, 0, dflag,
                                                    headp + 18320 + i*FHID,
                                                    headp + 18704 + i*FHID, al, ar);
        supergat_conv<<<(NN + 15)/16, 256, 0, stream>>>(hB, al, ar, rowdeg, colbuf,
                                                        biasv + (i+1)*FHID, hA);
    }

    pool_head<<<NGRAPH, 128, 0, stream>>>(hA, batch, headp, dflag, d_out);
}

// Round 10
// 385.366 us; speedup vs baseline: 1.2244x; 1.2244x over previous
//
#include <hip/hip_runtime.h>

#define NN 50000
#define EE 800000
#define FHID 128
#define NHEAD 4
#define NGRAPH 512
#define NCLS 10
#define BK 256            // buckets (dst>>8)
#define BCH 4096          // edges per block in bin kernel
#define NBLK_E 196        // ceil(EE/BCH)
#define NBUCK 196         // ceil(NN/256)
#define CAPB 6144         // slack capacity per bucket (mean 4096, 32-sigma headroom)

typedef unsigned short u16;
typedef unsigned int u32;
typedef unsigned long long u64;
typedef __attribute__((ext_vector_type(8))) short bf16x8;
typedef __attribute__((ext_vector_type(4))) float f32x4;

__device__ __forceinline__ float bf2f(u16 u){
    union { u32 i; float f; } v; v.i = ((u32)u) << 16; return v.f;
}
__device__ __forceinline__ float bflo(u32 u){
    union { u32 i; float f; } v; v.i = u << 16; return v.f;
}
__device__ __forceinline__ float bfhi(u32 u){
    union { u32 i; float f; } v; v.i = u & 0xffff0000u; return v.f;
}
__device__ __forceinline__ u16 f2bf(float f){
    union { float f; u32 i; } v; v.f = f;
    u32 r = v.i + 0x7fffu + ((v.i >> 16) & 1u);
    return (u16)(r >> 16);
}
__device__ __forceinline__ u32 pack2(float a, float b){
    return ((u32)f2bf(b) << 16) | f2bf(a);
}
__device__ __forceinline__ float loadF(const void* p, int i, int isf32){
    return isf32 ? ((const float*)p)[i] : bf2f(((const u16*)p)[i]);
}
__device__ __forceinline__ void unpk8(uint4 v, float* f){
    f[0]=bflo(v.x); f[1]=bfhi(v.x);
    f[2]=bflo(v.y); f[3]=bfhi(v.y);
    f[4]=bflo(v.z); f[5]=bfhi(v.z);
    f[6]=bflo(v.w); f[7]=bfhi(v.w);
}

// block-local dtype detect: count bf16-plausible halfwords in x[0..1023] (lds reduce)
__device__ int detect_local(const u16* x, int tid, int nthreads, int* lds){
    int ok = 0;
    for (int i = tid; i < 1024; i += nthreads){
        u16 u = x[i];
        int e = (u >> 7) & 0xFF;
        if ((u & 0x7fff) == 0 || (e >= 0x70 && e <= 0x85)) ok++;
    }
    lds[tid] = ok;
    __syncthreads();
    for (int o2 = nthreads >> 1; o2 > 0; o2 >>= 1){
        if (tid < o2) lds[tid] += lds[tid + o2];
        __syncthreads();
    }
    int r = (lds[0] < 900) ? 1 : 0;   // 1 = f32 inputs
    __syncthreads();
    return r;
}

// ---------------- fused prep: weights (blocks 0..511) + head/att (512..527) ---------
// block 0 also initializes gcur[t] = t*CAPB (slack-bucket bases)
__global__ __launch_bounds__(256) void prep_all(
        const u16* __restrict__ xz,
        const void* w_feat, const void* b_feat, const void* bn_feat_g, const void* bn_feat_b,
        const void* w_gat, const void* bn_conv_g, const void* bn_conv_b, const void* b_gat,
        const void* wfc, const void* bfc, const void* bnfg, const void* bnfb,
        const void* bnhg, const void* bnhb, const void* wcls, const void* bcls,
        const void* attl, const void* attr,
        u16* __restrict__ Wt, float* __restrict__ cvec, float* __restrict__ biasv,
        float* __restrict__ hp, int* __restrict__ dflag, int* __restrict__ gcur)
{
    __shared__ int ldsi[256];
    __shared__ float red[128];
    int bid = blockIdx.x, t = threadIdx.x;
    int isf32 = detect_local(xz, t, 256, ldsi);
    if (bid == 0){
        if (t == 0) dflag[0] = isf32;
        gcur[t] = t * CAPB;
    }

    if (bid < 512){
        if (t >= 128) return;
        int L = bid >> 7;
        int n = bid & 127;
        int k = t;
        const float rs = rsqrtf(1.0f + 1e-5f);
        float wv, bg, bb;
        if (L == 0){
            wv = loadF(w_feat, k*FHID + n, isf32);
            bg = loadF(bn_feat_g, k, isf32);
            bb = loadF(bn_feat_b, k, isf32);
        } else {
            wv = loadF(w_gat, (L-1)*FHID*FHID + k*FHID + n, isf32);
            bg = loadF(bn_conv_g, (L-1)*FHID + k, isf32);
            bb = loadF(bn_conv_b, (L-1)*FHID + k, isf32);
        }
        Wt[L*FHID*FHID + n*FHID + k] = f2bf(bg * rs * wv);
        red[k] = bb * wv;
        __syncthreads();
        for (int o2 = 64; o2 > 0; o2 >>= 1){
            if (k < o2) red[k] += red[k + o2];
            __syncthreads();
        }
        if (k == 0){
            float c = red[0];
            if (L == 0) c += loadF(b_feat, n, isf32);
            cvec[L*FHID + n] = c;
            if (L > 0) biasv[L*FHID + n] = loadF(b_gat, (L-1)*FHID + n, isf32);
        }
    } else {
        int gt = (bid - 512)*256 + t;
        for (int i = gt; i < FHID*FHID; i += 16*256) hp[i] = loadF(wfc, i, isf32);
        if (gt < FHID*NCLS) hp[16384 + gt] = loadF(wcls, gt, isf32);
        if (gt >= 2048 && gt < 2048 + 3*FHID){
            int i = gt - 2048;
            hp[18320 + i] = loadF(attl, i, isf32);
            hp[18704 + i] = loadF(attr, i, isf32);
        }
        if (gt >= 2560 && gt < 2560 + FHID){
            int tt = gt - 2560;
            hp[17664 + tt] = loadF(bnfg, tt, isf32);
            hp[17792 + tt] = loadF(bnfb, tt, isf32);
            hp[17920 + tt] = loadF(bfc,  tt, isf32);
            hp[18048 + tt] = loadF(bnhg, tt, isf32);
            hp[18176 + tt] = loadF(bnhb, tt, isf32);
        }
        if (gt >= 3072 && gt < 3072 + NCLS) hp[18304 + (gt - 3072)] = loadF(bcls, gt - 3072, isf32);
    }
}

// ---------------- MFMA GEMM: swapped operands + fused node_alpha epilogue -----------
__global__ __launch_bounds__(256) void gemm128(const void* __restrict__ A,
                                               const u16* __restrict__ Wt,
                                               const float* __restrict__ cvec,
                                               u16* __restrict__ out, int relu,
                                               int araw, const int* __restrict__ flag,
                                               const float* __restrict__ attl,
                                               const float* __restrict__ attr,
                                               float* __restrict__ al,
                                               float* __restrict__ ar)
{
    int wave = threadIdx.x >> 6;
    int lane = threadIdx.x & 63;
    int m = lane & 15, quad = lane >> 4;
    int rowbase = blockIdx.x * 128 + wave * 32;
    bool f32in = araw && flag[0];
    const u16*  Au = (const u16*)A;
    const float* Af = (const float*)A;
    int r0 = rowbase + m, r1 = rowbase + 16 + m;
    bool v0 = r0 < NN, v1 = r1 < NN;
    f32x4 acc[2][8];
#pragma unroll
    for (int i = 0; i < 2; i++)
#pragma unroll
        for (int j = 0; j < 8; j++) acc[i][j] = (f32x4){0.f,0.f,0.f,0.f};
#pragma unroll
    for (int t = 0; t < 4; t++){
        bf16x8 a0 = {0,0,0,0,0,0,0,0}, a1 = {0,0,0,0,0,0,0,0};
        int kof = t*32 + quad*8;
        if (f32in){
            if (v0){
                const float* p = Af + (size_t)r0*FHID + kof;
                float4 u0 = *(const float4*)p, u1 = *(const float4*)(p+4);
                a0[0]=(short)f2bf(u0.x); a0[1]=(short)f2bf(u0.y);
                a0[2]=(short)f2bf(u0.z); a0[3]=(short)f2bf(u0.w);
                a0[4]=(short)f2bf(u1.x); a0[5]=(short)f2bf(u1.y);
                a0[6]=(short)f2bf(u1.z); a0[7]=(short)f2bf(u1.w);
            }
            if (v1){
                const float* p = Af + (size_t)r1*FHID + kof;
                float4 u0 = *(const float4*)p, u1 = *(const float4*)(p+4);
                a1[0]=(short)f2bf(u0.x); a1[1]=(short)f2bf(u0.y);
                a1[2]=(short)f2bf(u0.z); a1[3]=(short)f2bf(u0.w);
                a1[4]=(short)f2bf(u1.x); a1[5]=(short)f2bf(u1.y);
                a1[6]=(short)f2bf(u1.z); a1[7]=(short)f2bf(u1.w);
            }
        } else {
            if (v0) a0 = *(const bf16x8*)(Au + (size_t)r0*FHID + kof);
            if (v1) a1 = *(const bf16x8*)(Au + (size_t)r1*FHID + kof);
        }
#pragma unroll
        for (int ct = 0; ct < 8; ct++){
            bf16x8 wfrag = *(const bf16x8*)(Wt + (ct*16 + m)*FHID + kof);
            acc[0][ct] = __builtin_amdgcn_mfma_f32_16x16x32_bf16(wfrag, a0, acc[0][ct], 0, 0, 0);
            acc[1][ct] = __builtin_amdgcn_mfma_f32_16x16x32_bf16(wfrag, a1, acc[1][ct], 0, 0, 0);
        }
    }
    bool doa = (attl != nullptr);
#pragma unroll
    for (int tt = 0; tt < 2; tt++){
        int row = rowbase + tt*16 + m;
        bool rv = row < NN;
        float sl[4] = {0.f,0.f,0.f,0.f};
        float sr[4] = {0.f,0.f,0.f,0.f};
#pragma unroll
        for (int ct = 0; ct < 8; ct++){
            int cb = ct*16 + quad*4;
            float4 cv = *(const float4*)(cvec + cb);
            float w0 = acc[tt][ct][0] + cv.x;
            float w1 = acc[tt][ct][1] + cv.y;
            float w2 = acc[tt][ct][2] + cv.z;
            float w3 = acc[tt][ct][3] + cv.w;
            if (relu){
                w0 = fmaxf(w0, 0.f); w1 = fmaxf(w1, 0.f);
                w2 = fmaxf(w2, 0.f); w3 = fmaxf(w3, 0.f);
            }
            if (doa){
                int h = ct >> 1;
                float4 tl = *(const float4*)(attl + cb);
                float4 tr = *(const float4*)(attr + cb);
                sl[h] += w0*tl.x + w1*tl.y + w2*tl.z + w3*tl.w;
                sr[h] += w0*tr.x + w1*tr.y + w2*tr.z + w3*tr.w;
            }
            if (rv){
                uint2 st; st.x = pack2(w0, w1); st.y = pack2(w2, w3);
                *(uint2*)(out + (size_t)row*FHID + cb) = st;
            }
        }
        if (doa){
#pragma unroll
            for (int h = 0; h < 4; h++){
                sl[h] += __shfl_xor(sl[h], 16, 64);
                sl[h] += __shfl_xor(sl[h], 32, 64);
                sr[h] += __shfl_xor(sr[h], 16, 64);
                sr[h] += __shfl_xor(sr[h], 32, 64);
            }
            if (rv){
                al[row*NHEAD + quad] = sl[quad];
                ar[row*NHEAD + quad] = sr[quad];
            }
        }
    }
}

// ---------------- bin edges into slack buckets (no global histogram needed) ---------
__global__ __launch_bounds__(256) void bin_edges(const int* __restrict__ srcp,
        const int* __restrict__ dstp, int* __restrict__ gcur, u64* __restrict__ binned)
{
    __shared__ int h[BK], lb[BK], gb[BK], cur[BK];
    __shared__ u64 stage[BCH];
    int t = threadIdx.x;
    h[t] = 0;
    __syncthreads();
    int base = blockIdx.x * BCH;
    int sv[16], dv[16];
#pragma unroll
    for (int k = 0; k < 16; k++){
        int e = base + k*256 + t;
        int d = -1, s = 0;
        if (e < EE){
            d = dstp[e]; s = srcp[e];
            if ((u32)d >= NN) d = -1;
        }
        sv[k] = s; dv[k] = d;
        if (d >= 0) atomicAdd(&h[d >> 8], 1);
    }
    __syncthreads();
    lb[t] = h[t];
    __syncthreads();
    for (int off = 1; off < BK; off <<= 1){
        int x = (t >= off) ? lb[t - off] : 0;
        __syncthreads();
        lb[t] += x;
        __syncthreads();
    }
    int excl = lb[t] - h[t];
    int tot  = lb[BK-1];
    __syncthreads();
    lb[t] = excl;
    gb[t] = h[t] ? atomicAdd(&gcur[t], h[t]) : 0;
    cur[t] = 0;
    __syncthreads();
#pragma unroll
    for (int k = 0; k < 16; k++){
        int d = dv[k];
        if (d >= 0){
            int b = d >> 8;
            int p = lb[b] + atomicAdd(&cur[b], 1);
            stage[p] = ((u64)(u32)d << 32) | (u32)sv[k];
        }
    }
    __syncthreads();
    for (int i = t; i < tot; i += 256){
        u64 pr = stage[i];
        int b = (int)(pr >> 40);
        binned[gb[b] + (i - lb[b])] = pr;
    }
}

// ---------------- per-bucket CSR: rowdeg int2 {start,end} into slack colbuf ---------
__global__ __launch_bounds__(256) void build_csr(const u64* __restrict__ binned,
        const int* __restrict__ gcur, int2* __restrict__ rowdeg, int* __restrict__ colbuf)
{
    __shared__ int deg[BK], ls[BK], cur[BK];
    __shared__ int colstage[CAPB];
    int b = blockIdx.x, t = threadIdx.x;
    int gb = b * CAPB;
    int cnt = gcur[b] - gb;
    if (cnt < 0) cnt = 0;
    if (cnt > CAPB) cnt = CAPB;
    deg[t] = 0;
    __syncthreads();
    for (int i = t; i < cnt; i += 256){
        int d = (int)(binned[gb + i] >> 32);
        atomicAdd(&deg[d & 255], 1);
    }
    __syncthreads();
    ls[t] = deg[t];
    __syncthreads();
    for (int off = 1; off < BK; off <<= 1){
        int x = (t >= off) ? ls[t - off] : 0;
        __syncthreads();
        ls[t] += x;
        __syncthreads();
    }
    int excl = ls[t] - deg[t];
    int node = b*256 + t;
    if (node < NN) rowdeg[node] = (int2){gb + excl, gb + excl + deg[t]};
    cur[t] = excl;
    __syncthreads();
    for (int i = t; i < cnt; i += 256){
        u64 pr = binned[gb + i];
        int d = (int)(pr >> 32) & 255;
        int s = (int)(u32)pr;
        int p = atomicAdd(&cur[d], 1);
        colstage[p] = s;
    }
    __syncthreads();
    for (int i = t; i < cnt; i += 256) colbuf[gb + i] = colstage[i];
}

// ---------------- SuperGAT conv: 4 nodes/wave, 16 lanes/node, 4-wide edge unroll ----
__global__ __launch_bounds__(256) void supergat_conv(const u16* __restrict__ hh,
        const float* __restrict__ al, const float* __restrict__ ar,
        const int2* __restrict__ rowdeg, const int* __restrict__ colbuf,
        const float* __restrict__ bias, u16* __restrict__ hout)
{
    int wid  = (blockIdx.x*256 + threadIdx.x) >> 6;
    int lane = threadIdx.x & 63;
    int group = lane >> 4;
    int gl    = lane & 15;
    int head  = gl >> 2;
    int q     = gl & 3;
    int node  = wid*4 + group;
    bool valid = node < NN;
    int snode = valid ? node : 0;
    int chbase = head*32 + q*8;

    uint4 hdv = *(const uint4*)(hh + (size_t)snode*FHID + chbase);
    float hd[8]; unpk8(hdv, hd);
    float arn = ar[snode*NHEAD + head];
    float aln = al[snode*NHEAD + head];

    float d = hd[0]*hd[0]+hd[1]*hd[1]+hd[2]*hd[2]+hd[3]*hd[3]
            + hd[4]*hd[4]+hd[5]*hd[5]+hd[6]*hd[6]+hd[7]*hd[7];
    d += __shfl_xor(d, 1, 64);
    d += __shfl_xor(d, 2, 64);
    float a = (aln + arn) * (1.0f / (1.0f + __expf(-d)));
    a = (a > 0.0f) ? a : 0.2f*a;
    float p = __expf(fminf(a, 60.f));
    float s = p;
    float o[8];
#pragma unroll
    for (int i = 0; i < 8; i++) o[i] = p*hd[i];

    int2 rd = valid ? rowdeg[node] : (int2){0,0};
    int e0 = rd.x, e1 = rd.y;
    if (e0 < 0) e0 = 0;
    if (e1 > BK*CAPB) e1 = BK*CAPB;

    int e = e0;
    while (e + 3 < e1){
        int sidx[4]; uint4 xv[4]; float af[4];
#pragma unroll
        for (int j = 0; j < 4; j++){
            int si = colbuf[e + j];
            if ((u32)si >= NN) si = 0;
            sidx[j] = si;
        }
#pragma unroll
        for (int j = 0; j < 4; j++){
            xv[j] = *(const uint4*)(hh + (size_t)sidx[j]*FHID + chbase);
            af[j] = al[sidx[j]*NHEAD + head];
        }
#pragma unroll
        for (int j = 0; j < 4; j++){
            float hs[8]; unpk8(xv[j], hs);
            float lg = hd[0]*hs[0]+hd[1]*hs[1]+hd[2]*hs[2]+hd[3]*hs[3]
                     + hd[4]*hs[4]+hd[5]*hs[5]+hd[6]*hs[6]+hd[7]*hs[7];
            lg += __shfl_xor(lg, 1, 64);
            lg += __shfl_xor(lg, 2, 64);
            float a2 = (af[j] + arn) * (1.0f / (1.0f + __expf(-lg)));
            a2 = (a2 > 0.0f) ? a2 : 0.2f*a2;
            float pe = __expf(fminf(a2, 60.f));
            s += pe;
#pragma unroll
            for (int i = 0; i < 8; i++) o[i] += pe*hs[i];
        }
        e += 4;
    }
    while (e < e1){
        int si = colbuf[e];
        if ((u32)si >= NN) si = 0;
        uint4 x1 = *(const uint4*)(hh + (size_t)si*FHID + chbase);
        float af1 = al[si*NHEAD + head];
        float hs[8]; unpk8(x1, hs);
        float lg = hd[0]*hs[0]+hd[1]*hs[1]+hd[2]*hs[2]+hd[3]*hs[3]
                 + hd[4]*hs[4]+hd[5]*hs[5]+hd[6]*hs[6]+hd[7]*hs[7];
        lg += __shfl_xor(lg, 1, 64);
        lg += __shfl_xor(lg, 2, 64);
        float a2 = (af1 + arn) * (1.0f / (1.0f + __expf(-lg)));
        a2 = (a2 > 0.0f) ? a2 : 0.2f*a2;
        float pe = __expf(fminf(a2, 60.f));
        s += pe;
#pragma unroll
        for (int i = 0; i < 8; i++) o[i] += pe*hs[i];
        e++;
    }

    if (valid){
        float inv = 1.0f / (s + 1e-16f);
        uint4 w;
        w.x = pack2(fmaxf(o[0]*inv + bias[chbase+0], 0.f),
                    fmaxf(o[1]*inv + bias[chbase+1], 0.f));
        w.y = pack2(fmaxf(o[2]*inv + bias[chbase+2], 0.f),
                    fmaxf(o[3]*inv + bias[chbase+3], 0.f));
        w.z = pack2(fmaxf(o[4]*inv + bias[chbase+4], 0.f),
                    fmaxf(o[5]*inv + bias[chbase+5], 0.f));
        w.w = pack2(fmaxf(o[6]*inv + bias[chbase+6], 0.f),
                    fmaxf(o[7]*inv + bias[chbase+7], 0.f));
        *(uint4*)(hout + (size_t)node*FHID + chbase) = w;
    }
}

// ---------------- fused pool + head: one block per graph ----------------------------
__global__ void pool_head(const u16* __restrict__ h, const int* __restrict__ batch,
                          const float* __restrict__ hp, const int* __restrict__ flag,
                          void* __restrict__ out)
{
    __shared__ int bounds[2];
    __shared__ float gb[FHID];
    __shared__ float g2[FHID];
    __shared__ float lg[16];
    int gi = blockIdx.x, t = threadIdx.x;
    int isf32 = flag[0];
    if (t < 2){
        int target = gi + t;
        int lo = 0, hi = NN;
        while (lo < hi){
            int mid = (lo + hi) >> 1;
            if (batch[mid] < target) lo = mid + 1; else hi = mid;
        }
        bounds[t] = lo;
    }
    __syncthreads();
    float acc0 = 0.f;
    for (int node = bounds[0]; node < bounds[1]; node++)
        acc0 += bf2f(h[(size_t)node*FHID + t]);
    const float rs = rsqrtf(1.0f + 1e-5f);
    gb[t] = acc0 * (hp[17664 + t] * rs) + hp[17792 + t];
    __syncthreads();
    float acc = hp[17920 + t];
    for (int k = 0; k < FHID; k++) acc += gb[k] * hp[k*FHID + t];
    acc = fmaxf(acc, 0.f);
    g2[t] = acc * (hp[18048 + t] * rs) + hp[18176 + t];
    __syncthreads();
    if (t < NCLS){
        float l = hp[18304 + t];
        for (int k = 0; k < FHID; k++) l += g2[k] * hp[16384 + k*NCLS + t];
        lg[t] = l;
    }
    __syncthreads();
    if (t == 0){
        float mx = lg[0];
        for (int j = 1; j < NCLS; j++) mx = fmaxf(mx, lg[j]);
        float se = 0.f;
        for (int j = 0; j < NCLS; j++) se += __expf(lg[j] - mx);
        float lse = logf(se) + mx;
        if (isf32){
            float* o = (float*)out;
            for (int j = 0; j < NCLS; j++) o[gi*NCLS + j] = lg[j] - lse;
            if (gi == 0) o[NGRAPH*NCLS] = 0.f;
        } else {
            u16* o = (u16*)out;
            for (int j = 0; j < NCLS; j++) o[gi*NCLS + j] = f2bf(lg[j] - lse);
            if (gi == 0) o[NGRAPH*NCLS] = 0;
        }
    }
}

extern "C" void kernel_launch(void* const* d_in, const int* in_sizes, int n_in,
                              void* d_out, int out_size, void* d_ws, size_t ws_size,
                              hipStream_t stream)
{
    (void)in_sizes; (void)n_in; (void)out_size; (void)ws_size;
    const void* x         = d_in[0];
    const int* edge       = (const int*)d_in[1];
    const int* batch      = (const int*)d_in[2];

    char* ws = (char*)d_ws;
    size_t off = 0;
    auto alloc = [&](size_t bytes) -> char* {
        char* p = ws + off; off += (bytes + 255) & ~(size_t)255; return p;
    };
    int*   dflag   = (int*)  alloc(256);
    u16*   WtAll   = (u16*)  alloc((size_t)4*FHID*FHID*2);
    float* cvecAll = (float*)alloc((size_t)4*FHID*4);
    float* biasv   = (float*)alloc((size_t)4*FHID*4);
    float* headp   = (float*)alloc((size_t)19088*4);
    float* al      = (float*)alloc((size_t)NN*NHEAD*4);
    float* ar      = (float*)alloc((size_t)NN*NHEAD*4);
    int*   gcur    = (int*)  alloc((size_t)BK*4);
    int2*  rowdeg  = (int2*) alloc((size_t)NN*8);
    int*   colbuf  = (int*)  alloc((size_t)BK*CAPB*4);     // 6.3 MB slack layout
    u16*   hA      = (u16*)  alloc((size_t)NN*FHID*2);
    u16*   hB      = (u16*)  alloc((size_t)NN*FHID*2);
    // binned (256*6144*8 = 12.58 MB) aliases hB (12.8 MB): hB first written by the
    // layer-1 gemm, strictly after build_csr (stream-ordered).
    u64*   binned  = (u64*)hB;

    const int* srcp = edge;
    const int* dstp = edge + EE;

    prep_all<<<528, 256, 0, stream>>>((const u16*)x,
        d_in[5], d_in[6], d_in[3], d_in[4], d_in[9], d_in[7], d_in[8], d_in[12],
        d_in[15], d_in[16], d_in[13], d_in[14], d_in[17], d_in[18], d_in[19], d_in[20],
        d_in[10], d_in[11],
        WtAll, cvecAll, biasv, headp, dflag, gcur);

    bin_edges<<<NBLK_E, 256, 0, stream>>>(srcp, dstp, gcur, binned);
    build_csr<<<NBUCK, 256, 0, stream>>>(binned, gcur, rowdeg, colbuf);

    // feature layer: reads raw x (f32 or bf16 per flag), converts in-register
    gemm128<<<(NN + 127)/128, 256, 0, stream>>>(x, WtAll, cvecAll, hA, 1, 1, dflag,
                                                nullptr, nullptr, nullptr, nullptr);

    for (int i = 0; i < 3; i++){
        gemm128<<<(NN + 127)/128, 256, 0, stream>>>(hA, WtAll + (i+1)*FHID*FHID,
                                                    cvecAll + (i+1)*FHID, hB, 0, 0, dflag,
                                                    headp + 18320 + i*FHID,
                                                    headp + 18704 + i*FHID, al, ar);
        supergat_conv<<<(NN + 15)/16, 256, 0, stream>>>(hB, al, ar, rowdeg, colbuf,
                                                        biasv + (i+1)*FHID, hA);
    }

    pool_head<<<NGRAPH, 128, 0, stream>>>(hA, batch, headp, dflag, d_out);
}